// Round 6
// baseline (336.028 us; speedup 1.0000x reference)
//
#include <hip/hip_runtime.h>
#include <hip/hip_bf16.h>

#define D  128
#define KN 32
#define LST 136   // LDS row stride in ushorts: 272 B = 17*16 B (16B-aligned, bank-shifted)

typedef __attribute__((ext_vector_type(8))) short bf16x8;
typedef __attribute__((ext_vector_type(4))) float f32x4;

static __device__ __forceinline__ unsigned short f2bf(float f) {
    union { float f; unsigned int u; } v; v.f = f;
    unsigned int u = v.u;
    u += 0x7fff + ((u >> 16) & 1);   // RNE
    return (unsigned short)(u >> 16);
}
static __device__ __forceinline__ float bf2f(unsigned short h) {
    union { float f; unsigned int u; } v; v.u = ((unsigned int)h) << 16;
    return v.f;
}
// packed RNE fp32x2 -> bf16x2 (v_cvt_pk_bf16_f32)
static __device__ __forceinline__ unsigned int pk2bf(float a, float b) {
    float2 t; t.x = a; t.y = b;
    __hip_bfloat162 h = __float22bfloat162_rn(t);
    union { __hip_bfloat162 h; unsigned int u; } v; v.h = h;
    return v.u;
}

// One-shot: transpose+convert W1 halves and W2 into bf16 [col][k] layouts.
__global__ __launch_bounds__(256) void wt_kernel(
    const float* __restrict__ W1, const float* __restrict__ W2,
    unsigned short* __restrict__ W1Tt, unsigned short* __restrict__ W1Tb,
    unsigned short* __restrict__ W2T)
{
    int idx = blockIdx.x * 256 + threadIdx.x;
    if (idx < D * D) {
        int col = idx >> 7, e = idx & 127;
        W1Tt[col * D + e] = f2bf(W1[e * D + col]);
        W1Tb[col * D + e] = f2bf(W1[(D + e) * D + col]);
        W2T [col * D + e] = f2bf(W2[e * D + col]);
    }
}

// Q = emb[vnodes] @ W1bot + b1  (fp32 out; small: 20000 x 128)
__global__ __launch_bounds__(256) void q_kernel(
    const float* __restrict__ emb, const int* __restrict__ vnodes, int NN,
    const unsigned short* __restrict__ W1Tb, const float* __restrict__ b1,
    float* __restrict__ Qf)
{
    __shared__ unsigned short sA[128][LST];

    const int tid  = threadIdx.x;
    const int lane = tid & 63;
    const int w    = tid >> 6;
    const int m    = lane & 15, q = lane >> 4;
    const int r0   = blockIdx.x * 128;

#pragma unroll
    for (int i = 0; i < 16; ++i) {
        int e = tid + 256 * i;
        int row = e >> 5, c4 = (e & 31) << 2;
        int r = r0 + row; if (r > NN - 1) r = NN - 1;
        int vr = vnodes[r];
        const float4 f = *(const float4*)(emb + (long)vr * D + c4);
        ushort4 h;
        h.x = f2bf(f.x); h.y = f2bf(f.y); h.z = f2bf(f.z); h.w = f2bf(f.w);
        *(ushort4*)(&sA[row][c4]) = h;
    }
    __syncthreads();

    bf16x8 Bf[2][4];
#pragma unroll
    for (int nt = 0; nt < 2; ++nt)
#pragma unroll
        for (int kk = 0; kk < 4; ++kk)
            Bf[nt][kk] = *(const bf16x8*)(W1Tb + (32 * w + 16 * nt + m) * D + kk * 32 + q * 8);
    float bv[2];
#pragma unroll
    for (int nt = 0; nt < 2; ++nt) bv[nt] = b1[32 * w + 16 * nt + m];

    f32x4 acc[8][2];
#pragma unroll
    for (int mt = 0; mt < 8; ++mt)
#pragma unroll
        for (int nt = 0; nt < 2; ++nt) acc[mt][nt] = (f32x4){0.f, 0.f, 0.f, 0.f};

#pragma unroll
    for (int kk = 0; kk < 4; ++kk)
#pragma unroll
        for (int mt = 0; mt < 8; ++mt) {
            bf16x8 a = *(const bf16x8*)(&sA[16 * mt + m][kk * 32 + q * 8]);
            acc[mt][0] = __builtin_amdgcn_mfma_f32_16x16x32_bf16(a, Bf[0][kk], acc[mt][0], 0, 0, 0);
            acc[mt][1] = __builtin_amdgcn_mfma_f32_16x16x32_bf16(a, Bf[1][kk], acc[mt][1], 0, 0, 0);
        }

#pragma unroll
    for (int mt = 0; mt < 8; ++mt)
#pragma unroll
        for (int nt = 0; nt < 2; ++nt) {
            int col = 32 * w + 16 * nt + m;
#pragma unroll
            for (int r = 0; r < 4; ++r) {
                int row = r0 + 16 * mt + 4 * q + r;
                if (row < NN) Qf[(long)row * D + col] = acc[mt][nt][r] + bv[nt];
            }
        }
}

// Fully-fused aggregator. Per iteration (4 nodes):
//   stage: gather 128 raw emb rows -> bf16 sU (=Eg) + sQf
//   gv prefetch (aggregation slice, registers) ; layer-1 MFMA (A=W1T regs, B=sU)
//   barrier ; write X=relu(acc1+Qf) into the SAME sU buffer (Eg dead: gv captured)
//   barrier ; layer-2 MFMA (A=sU, B=W2T regs) + score reduce
//   barrier ; softmax ; barrier ; aggregation from gv regs.
// One 34.8 KB LDS buffer -> 39.4 KB total -> 4 blocks/CU.
__global__ __launch_bounds__(256, 3) void agg_kernel(
    const float* __restrict__ emb, const int* __restrict__ nidx,
    const unsigned short* __restrict__ W1Tt, const unsigned short* __restrict__ W2T,
    const float* __restrict__ b2, const float* __restrict__ W3,
    const float* __restrict__ b3, const float* __restrict__ Qf,
    float* __restrict__ out, int NN)
{
    __shared__ unsigned short sU[128][LST];   // Eg, then X (overlaid)
    __shared__ float sQf[4][D];
    __shared__ float sSp[4][128];
    __shared__ float sAtt[128];

    const int tid  = threadIdx.x;
    const int lane = tid & 63;
    const int w    = tid >> 6;          // wave index == node sub-index
    const int m    = lane & 15, q = lane >> 4;

    // persistent fragments: W1T as layer-1 A (this wave's 32 X-cols),
    // W2T as layer-2 B (this wave's 32 H-cols)
    bf16x8 Af[2][4], Bf[2][4];
#pragma unroll
    for (int t = 0; t < 2; ++t)
#pragma unroll
        for (int kk = 0; kk < 4; ++kk) {
            Af[t][kk] = *(const bf16x8*)(W1Tt + (32 * w + 16 * t + m) * D + kk * 32 + q * 8);
            Bf[t][kk] = *(const bf16x8*)(W2T  + (32 * w + 16 * t + m) * D + kk * 32 + q * 8);
        }
    float b2v[2], w3v[2];
#pragma unroll
    for (int nt = 0; nt < 2; ++nt) {
        int col = 32 * w + 16 * nt + m;
        b2v[nt] = b2[col];
        w3v[nt] = W3[col];
    }
    const float b3s = b3[0];

    const int groups = (NN + 3) >> 2;
    for (int g = blockIdx.x; g < groups; g += gridDim.x) {
        const int node0 = g * 4;

        // ---- stage sQf (coalesced) ----
        {
            int i2 = tid * 2, nd = i2 >> 7, c = i2 & 127;
            int ndg = node0 + nd; if (ndg > NN - 1) ndg = NN - 1;
            *(float2*)(&sQf[nd][c]) = *(const float2*)(Qf + (long)ndg * D + c);
        }
        // ---- stage sU = bf16(emb[nidx]) : 2 threads/row, fp32 gather ----
        {
            int row = tid >> 1, half = tid & 1;
            int ndg = node0 + (row >> 5); if (ndg > NN - 1) ndg = NN - 1;
            int ni = nidx[ndg * KN + (row & 31)];
            const float* src = emb + (long)ni * D + half * 64;
#pragma unroll
            for (int j = 0; j < 8; ++j) {
                float4 f0 = *(const float4*)(src + j * 8);
                float4 f1 = *(const float4*)(src + j * 8 + 4);
                uint4 pk;
                pk.x = pk2bf(f0.x, f0.y); pk.y = pk2bf(f0.z, f0.w);
                pk.z = pk2bf(f1.x, f1.y); pk.w = pk2bf(f1.z, f1.w);
                *(uint4*)(&sU[row][half * 64 + j * 8]) = pk;
            }
        }
        __syncthreads();   // B1: sU(=Eg), sQf ready

        // ---- aggregation prefetch: node w's rows into registers ----
        bf16x8 gv[8];
#pragma unroll
        for (int j = 0; j < 8; ++j)
            gv[j] = *(const bf16x8*)(&sU[w * KN + (lane >> 4) + 4 * j][(lane & 15) * 8]);

        // ---- layer-1: Xt = W1T @ Eg^T, all 4 nodes, acc in regs ----
        f32x4 acc1[4][2][2];
#pragma unroll
        for (int nd = 0; nd < 4; ++nd)
#pragma unroll
            for (int t = 0; t < 2; ++t)
#pragma unroll
                for (int nt = 0; nt < 2; ++nt) acc1[nd][t][nt] = (f32x4){0.f, 0.f, 0.f, 0.f};

#pragma unroll
        for (int nd = 0; nd < 4; ++nd)
#pragma unroll
            for (int kk = 0; kk < 4; ++kk) {
                bf16x8 e0 = *(const bf16x8*)(&sU[nd * 32 + m][kk * 32 + q * 8]);
                bf16x8 e1 = *(const bf16x8*)(&sU[nd * 32 + 16 + m][kk * 32 + q * 8]);
                acc1[nd][0][0] = __builtin_amdgcn_mfma_f32_16x16x32_bf16(Af[0][kk], e0, acc1[nd][0][0], 0, 0, 0);
                acc1[nd][1][0] = __builtin_amdgcn_mfma_f32_16x16x32_bf16(Af[1][kk], e0, acc1[nd][1][0], 0, 0, 0);
                acc1[nd][0][1] = __builtin_amdgcn_mfma_f32_16x16x32_bf16(Af[0][kk], e1, acc1[nd][0][1], 0, 0, 0);
                acc1[nd][1][1] = __builtin_amdgcn_mfma_f32_16x16x32_bf16(Af[1][kk], e1, acc1[nd][1][1], 0, 0, 0);
            }
        __syncthreads();   // B2: all sU(=Eg) reads done (gv captured)

        // ---- write X = relu(acc1 + Qf) into sU (now =X) ----
        // D-layout: col=lane&15 -> neighbor row, row=4q+r -> X-col
#pragma unroll
        for (int nd = 0; nd < 4; ++nd)
#pragma unroll
            for (int t = 0; t < 2; ++t) {
                int xc = 32 * w + 16 * t + 4 * q;
                float q0 = sQf[nd][xc], q1 = sQf[nd][xc + 1];
                float q2 = sQf[nd][xc + 2], q3 = sQf[nd][xc + 3];
#pragma unroll
                for (int nt = 0; nt < 2; ++nt) {
                    float v0 = fmaxf(acc1[nd][t][nt][0] + q0, 0.f);
                    float v1 = fmaxf(acc1[nd][t][nt][1] + q1, 0.f);
                    float v2 = fmaxf(acc1[nd][t][nt][2] + q2, 0.f);
                    float v3 = fmaxf(acc1[nd][t][nt][3] + q3, 0.f);
                    uint2 pk; pk.x = pk2bf(v0, v1); pk.y = pk2bf(v2, v3);
                    *(uint2*)(&sU[nd * 32 + 16 * nt + m][xc]) = pk;
                }
            }
        __syncthreads();   // B3: sU(=X) ready

        // ---- layer-2: H = X @ W2 (this wave's 32 cols) + score ----
        f32x4 acc[8][2];
#pragma unroll
        for (int mt = 0; mt < 8; ++mt)
#pragma unroll
            for (int nt = 0; nt < 2; ++nt) acc[mt][nt] = (f32x4){0.f, 0.f, 0.f, 0.f};

#pragma unroll
        for (int kk = 0; kk < 4; ++kk)
#pragma unroll
            for (int mt = 0; mt < 8; ++mt) {
                bf16x8 a = *(const bf16x8*)(&sU[16 * mt + m][kk * 32 + q * 8]);
                acc[mt][0] = __builtin_amdgcn_mfma_f32_16x16x32_bf16(a, Bf[0][kk], acc[mt][0], 0, 0, 0);
                acc[mt][1] = __builtin_amdgcn_mfma_f32_16x16x32_bf16(a, Bf[1][kk], acc[mt][1], 0, 0, 0);
            }

#pragma unroll
        for (int mt = 0; mt < 8; ++mt) {
            float p[4];
#pragma unroll
            for (int r = 0; r < 4; ++r) {
                float h0 = acc[mt][0][r] + b2v[0]; h0 = h0 > 0.f ? h0 : 0.f;
                float h1 = acc[mt][1][r] + b2v[1]; h1 = h1 > 0.f ? h1 : 0.f;
                p[r] = h0 * w3v[0] + h1 * w3v[1];
            }
#pragma unroll
            for (int off = 8; off >= 1; off >>= 1)
#pragma unroll
                for (int r = 0; r < 4; ++r) p[r] += __shfl_xor(p[r], off, 16);
            if (m == 0) {
#pragma unroll
                for (int r = 0; r < 4; ++r) sSp[w][16 * mt + 4 * q + r] = p[r];
            }
        }
        __syncthreads();   // B4: sSp ready

        // ---- softmax: 128 scores = 4 nodes x 32 neighbors ----
        if (tid < 128) {
            float s = sSp[0][tid] + sSp[1][tid] + sSp[2][tid] + sSp[3][tid] + b3s;
            float mx = s;
#pragma unroll
            for (int off = 16; off >= 1; off >>= 1) mx = fmaxf(mx, __shfl_xor(mx, off, 32));
            float e = __expf(s - mx);
            float sum = e;
#pragma unroll
            for (int off = 16; off >= 1; off >>= 1) sum += __shfl_xor(sum, off, 32);
            sAtt[tid] = e / sum;
        }
        __syncthreads();   // B5: sAtt ready

        // ---- aggregation: node w per wave, from gv registers ----
        {
            float r[8] = {0.f, 0.f, 0.f, 0.f, 0.f, 0.f, 0.f, 0.f};
#pragma unroll
            for (int j = 0; j < 8; ++j) {
                float a = sAtt[w * KN + (lane >> 4) + 4 * j];
#pragma unroll
                for (int h = 0; h < 8; ++h)
                    r[h] += a * bf2f((unsigned short)gv[j][h]);
            }
#pragma unroll
            for (int h = 0; h < 8; ++h) {
                r[h] += __shfl_xor(r[h], 16);
                r[h] += __shfl_xor(r[h], 32);
            }
            int ndw = node0 + w;
            if (lane < 16 && ndw < NN) {
                float4 o0 = {r[0], r[1], r[2], r[3]};
                float4 o1 = {r[4], r[5], r[6], r[7]};
                *(float4*)(out + (long)ndw * D + lane * 8)     = o0;
                *(float4*)(out + (long)ndw * D + lane * 8 + 4) = o1;
            }
        }
        // no trailing barrier: next stage writes sU/sQf, whose last reads
        // (layer-2 / layer-1-epilogue) are >=2 barriers back; agg reads only
        // registers + sAtt (next sAtt write is after next B4).
    }
}

// Correct-but-slow fp32 VALU fallback (only if ws is too small).
__global__ __launch_bounds__(128) void naive_kernel(
    const float* __restrict__ emb, const int* __restrict__ vnodes,
    const int* __restrict__ nidx,
    const float* __restrict__ W1, const float* __restrict__ b1,
    const float* __restrict__ W2, const float* __restrict__ b2,
    const float* __restrict__ W3, const float* __restrict__ b3,
    float* __restrict__ out)
{
    __shared__ float sE[KN + 1][D];
    __shared__ float sH[KN][D];
    __shared__ float sH2[KN][D];
    __shared__ float sS[KN];
    __shared__ float sA2[KN];
    const int node = blockIdx.x, tid = threadIdx.x;

    for (int r = 0; r < KN + 1; ++r) {
        int vr = (r < KN) ? nidx[node * KN + r] : vnodes[node];
        sE[r][tid] = emb[(long)vr * D + tid];
    }
    __syncthreads();
    for (int k = 0; k < KN; ++k) {
        float s = b1[tid];
        for (int e = 0; e < D; ++e) s += sE[k][e]  * W1[e * D + tid];
        for (int e = 0; e < D; ++e) s += sE[KN][e] * W1[(D + e) * D + tid];
        sH[k][tid] = s > 0.f ? s : 0.f;
    }
    __syncthreads();
    for (int k = 0; k < KN; ++k) {
        float s = b2[tid];
        for (int e = 0; e < D; ++e) s += sH[k][e] * W2[e * D + tid];
        sH2[k][tid] = s > 0.f ? s : 0.f;
    }
    __syncthreads();
    if (tid < KN) {
        float s = b3[0];
        for (int e = 0; e < D; ++e) s += sH2[tid][e] * W3[e];
        sS[tid] = s;
    }
    __syncthreads();
    if (tid == 0) {
        float mx = sS[0];
        for (int k = 1; k < KN; ++k) mx = fmaxf(mx, sS[k]);
        float sum = 0.f;
        for (int k = 0; k < KN; ++k) { sA2[k] = __expf(sS[k] - mx); sum += sA2[k]; }
        for (int k = 0; k < KN; ++k) sA2[k] /= sum;
    }
    __syncthreads();
    float a = 0.f;
    for (int k = 0; k < KN; ++k) a += sA2[k] * sE[k][tid];
    out[(long)node * D + tid] = a;
}

extern "C" void kernel_launch(void* const* d_in, const int* in_sizes, int n_in,
                              void* d_out, int out_size, void* d_ws, size_t ws_size,
                              hipStream_t stream) {
    const float* emb    = (const float*)d_in[0];
    const int*   vnodes = (const int*)d_in[1];
    const int*   nidx   = (const int*)d_in[2];
    const float* W1     = (const float*)d_in[3];
    const float* b1     = (const float*)d_in[4];
    const float* W2     = (const float*)d_in[5];
    const float* b2     = (const float*)d_in[6];
    const float* W3     = (const float*)d_in[7];
    const float* b3     = (const float*)d_in[8];
    float* out = (float*)d_out;

    const int NN = in_sizes[1];       // 20000

    const size_t q_bytes  = (size_t)NN * D * sizeof(float);
    const size_t wt_elems = (size_t)D * D;
    const size_t need = q_bytes + 3 * wt_elems * sizeof(unsigned short);

    if (ws_size >= need) {
        float* Qf            = (float*)d_ws;
        unsigned short* W1Tt = (unsigned short*)((char*)d_ws + q_bytes);
        unsigned short* W1Tb = W1Tt + wt_elems;
        unsigned short* W2T  = W1Tb + wt_elems;

        wt_kernel<<<(D * D + 255) / 256, 256, 0, stream>>>(W1, W2, W1Tt, W1Tb, W2T);
        q_kernel<<<(NN + 127) / 128, 256, 0, stream>>>(emb, vnodes, NN, W1Tb, b1, Qf);
        agg_kernel<<<2048, 256, 0, stream>>>(
            emb, nidx, W1Tt, W2T, b2, W3, b3, Qf, out, NN);
    } else {
        naive_kernel<<<NN, D, 0, stream>>>(emb, vnodes, nidx, W1, b1, W2, b2, W3, b3, out);
    }
}